// Round 5
// baseline (8600.298 us; speedup 1.0000x reference)
//
#include <hip/hip_runtime.h>

#define HDIM   256
#define NLAYER 10
#define BATCH  256
#define TSTEPS 512
#define NTHR   512
#define DEPTH  3
#define NB_REC   160            // (l, s16): M=16 rows each
#define NB_FEED  72             // l=1..9, j=0..7: M=32 rows each
#define NB_FEED0 24             // l=0: j=0..7 x 3 t-phases
#define NB_ALL   256

typedef __attribute__((ext_vector_type(8))) short short8;
typedef __attribute__((ext_vector_type(4))) float f32x4;

// ---------- bf16 helpers ----------
__device__ __forceinline__ unsigned short bf16_rne(float f) {
    unsigned v = __float_as_uint(f);
    unsigned r = v + 0x7FFFu + ((v >> 16) & 1u);
    return (unsigned short)(r >> 16);
}
__device__ __forceinline__ float bf16_f(unsigned short b) {
    return __uint_as_float(((unsigned)b) << 16);
}
__device__ __forceinline__ float fast_tanh(float v) {
    float a = fabsf(v);
    float e = __expf(-2.0f * a);
    float r = (1.0f - e) / (1.0f + e);
    return __builtin_copysignf(r, v);
}
__device__ __forceinline__ void cvt8(const float* __restrict__ p, short8& hi, short8& lo) {
#pragma unroll
    for (int e = 0; e < 8; ++e) {
        float f = p[e];
        unsigned short h = bf16_rne(f);
        hi[e] = (short)h;
        lo[e] = (short)bf16_rne(f - bf16_f(h));
    }
}

#define MFMA16(a, b, c) __builtin_amdgcn_mfma_f32_16x16x32_bf16((a), (b), (c), 0, 0, 0)

__device__ __forceinline__ void wait_ge(int* f, int need) {
    while (__hip_atomic_load(f, __ATOMIC_RELAXED, __HIP_MEMORY_SCOPE_AGENT) < need)
        __builtin_amdgcn_s_sleep(1);
}
#define AT_LD(p)      __hip_atomic_load((p), __ATOMIC_RELAXED, __HIP_MEMORY_SCOPE_AGENT)
#define AT_ST(p, v)   __hip_atomic_store((p), (v), __ATOMIC_RELAXED, __HIP_MEMORY_SCOPE_AGENT)
#define VMDRAIN()     asm volatile("s_waitcnt vmcnt(0)" ::: "memory")

// packed x (hi|lo<<16) -> two short8 fragments, via sc1 (L3-coherent) loads
__device__ __forceinline__ void ld_x8(unsigned long long* p, short8& xh, short8& xl) {
#pragma unroll
    for (int q = 0; q < 4; ++q) {
        unsigned long long w = AT_LD(p + q);
        unsigned a = (unsigned)w, b = (unsigned)(w >> 32);
        xh[2 * q]     = (short)(a & 0xffffu);
        xl[2 * q]     = (short)(a >> 16);
        xh[2 * q + 1] = (short)(b & 0xffffu);
        xl[2 * q + 1] = (short)(b >> 16);
    }
}

// stage 256x256 fp32 weight matrix -> LDS bf16-hi, XOR-swizzled
__device__ __forceinline__ void stage_whi_f32(const float* __restrict__ src, char* smem, int tid) {
    for (int i = 0; i < 16; ++i) {
        const int c = tid + i * NTHR;
        const int r = c >> 5;
        const int kb = c & 31;
        short8 hi, lo;
        cvt8(src + (size_t)r * HDIM + kb * 8, hi, lo);
        *(short8*)(smem + r * 512 + ((kb * 16) ^ ((r & 7) << 4))) = hi;
    }
}

// ---------- single cooperative kernel, two roles, fence-free flag pipeline ----------
__global__ void __launch_bounds__(NTHR, 1) rnn_pipe(
    const int* __restrict__ tokens, const float* __restrict__ hidden0,
    const float* __restrict__ emb,
    const float* __restrict__ Wx_w, const float* __restrict__ Wx_b,
    const float* __restrict__ Wh_w, const float* __restrict__ Wh_b,
    float* __restrict__ u,            // [DEPTH][160 chains][16x256] fp32, fragment-linear
    unsigned* __restrict__ hg,        // [DEPTH][9 planes][256 rows][256 cols] packed hi|lo
    int* __restrict__ fu,             // [80][TSTEPS]  (feed published)
    int* __restrict__ fh,             // [160][TSTEPS] (rec published)
    float* __restrict__ out) {
    const int bid = blockIdx.x;
    const int tid = threadIdx.x;
    const int wv = tid >> 6;
    const int lane = tid & 63;
    const int ln15 = lane & 15;
    const int kq = (lane >> 4) << 3;           // k element sub-offset
    const int hi16 = (lane >> 4) << 4;         // k byte sub-offset
    const int swz = (ln15 & 7) << 4;

    __shared__ char smem[131072];
    float* hfinal = out + (size_t)BATCH * TSTEPS * HDIM;

    if (bid < NB_REC) {
        // ================= recurrence wg: 16 rows, Wh in registers =================
        const int l = bid >> 4, s16 = bid & 15;
        const int row0g = s16 * 16;
        // Wh hi/lo -> VGPRs (wave wv owns output cols [32wv, 32wv+32))
        short8 whh[2][8], whl[2][8];
#pragma unroll
        for (int ni = 0; ni < 2; ++ni)
#pragma unroll
            for (int kc = 0; kc < 8; ++kc)
                cvt8(Wh_w + (size_t)l * 65536 + (size_t)(wv * 32 + ni * 16 + ln15) * HDIM + kc * 32 + kq,
                     whh[ni][kc], whl[ni][kc]);
        // stage h(-1): 16 rows x 32 chunks = 512 chunks, one per thread
        {
            const int r = tid >> 5, kb = tid & 31;
            short8 hi, lo;
            cvt8(hidden0 + ((size_t)(l * BATCH + row0g + r)) * HDIM + kb * 8, hi, lo);
            const int so = r * 512 + ((kb * 16) ^ ((r & 7) << 4));
            *(short8*)(smem + so) = hi;
            *(short8*)(smem + 8192 + so) = lo;
        }
        __syncthreads();

        int* fuMe = fu + ((l << 3) + (s16 >> 1)) * TSTEPS;
        int* fhMe = fh + bid * TSTEPS;
        int* fuNx = (l < NLAYER - 1) ? fu + (((l + 1) << 3) + (s16 >> 1)) * TSTEPS : nullptr;

        for (int t = 0; t < TSTEPS; ++t) {
            if (tid == 0) {
                wait_ge(fuMe + t, 1);                       // u(l,t) ready
                if (fuNx && t >= DEPTH) wait_ge(fuNx + t - DEPTH, 1);  // hg slot free
            }
            __syncthreads();
            // u frags (sc1 loads, issued early)
            unsigned long long* us = (unsigned long long*)(u + ((size_t)(t % DEPTH) * NB_REC + bid) * 4096);
            f32x4 uv[2];
#pragma unroll
            for (int ni = 0; ni < 2; ++ni) {
                const size_t ix = ((size_t)((wv * 2 + ni) * 64 + lane)) * 2;
                unsigned long long q0 = AT_LD(us + ix);
                unsigned long long q1 = AT_LD(us + ix + 1);
                uv[ni][0] = __uint_as_float((unsigned)q0);
                uv[ni][1] = __uint_as_float((unsigned)(q0 >> 32));
                uv[ni][2] = __uint_as_float((unsigned)q1);
                uv[ni][3] = __uint_as_float((unsigned)(q1 >> 32));
            }
            // h(t-1) @ Wh^T   (A from LDS, B from VGPRs, 3-term hi/lo)
            f32x4 acc[2] = {};
#pragma unroll
            for (int kc = 0; kc < 8; ++kc) {
                const int kb = (kc * 64 + hi16) ^ swz;
                const short8 ah = *(const short8*)(smem + ln15 * 512 + kb);
                const short8 al = *(const short8*)(smem + 8192 + ln15 * 512 + kb);
                acc[0] = MFMA16(ah, whh[0][kc], acc[0]);
                acc[1] = MFMA16(ah, whh[1][kc], acc[1]);
                acc[0] = MFMA16(ah, whl[0][kc], acc[0]);
                acc[1] = MFMA16(ah, whl[1][kc], acc[1]);
                acc[0] = MFMA16(al, whh[0][kc], acc[0]);
                acc[1] = MFMA16(al, whh[1][kc], acc[1]);
            }
            __syncthreads();   // all h(t-1) reads done before overwrite
            // epilogue
            unsigned* hgp = (l < NLAYER - 1)
                ? hg + ((size_t)(t % DEPTH) * 9 + l) * 65536 : nullptr;
#pragma unroll
            for (int ni = 0; ni < 2; ++ni) {
                const int col = wv * 32 + ni * 16 + ln15;
#pragma unroll
                for (int r = 0; r < 4; ++r) {
                    const int row = ((lane >> 4) << 2) + r;
                    const float y = fast_tanh(acc[ni][r] + uv[ni][r]);
                    const unsigned short yh = bf16_rne(y);
                    const unsigned short yl = bf16_rne(y - bf16_f(yh));
                    const int so = row * 512 + ((2 * col) ^ ((row & 7) << 4));
                    *(unsigned short*)(smem + so) = yh;
                    *(unsigned short*)(smem + 8192 + so) = yl;
                    if (hgp) {
                        AT_ST(hgp + (size_t)(row0g + row) * HDIM + col,
                              (unsigned)yh | ((unsigned)yl << 16));
                    } else {
                        out[((size_t)(row0g + row) * TSTEPS + t) * HDIM + col] = y;
                    }
                    if (t == TSTEPS - 1)
                        hfinal[((size_t)l * BATCH + row0g + row) * HDIM + col] = y;
                }
            }
            VMDRAIN();
            __syncthreads();   // all waves' stores at L3
            if (tid == 0)
                __hip_atomic_fetch_add(fhMe + t, 1, __ATOMIC_RELAXED, __HIP_MEMORY_SCOPE_AGENT);
        }
    } else {
        // ================= feed wg: 32 rows, u(t) = x(t) @ Wx^T + b =================
        int l, j, t0, tstr;
        if (bid < NB_REC + NB_FEED) {
            const int id = bid - NB_REC;
            l = 1 + (id >> 3); j = id & 7; t0 = 0; tstr = 1;
        } else {
            const int id = bid - (NB_REC + NB_FEED);
            l = 0; j = id & 7; t0 = id >> 3; tstr = 3;       // 3 t-phases for layer 0
        }
        stage_whi_f32(Wx_w + (size_t)l * 65536, smem, tid);
        short8 wxl[2][8];
#pragma unroll
        for (int ni = 0; ni < 2; ++ni)
#pragma unroll
            for (int kc = 0; kc < 8; ++kc) {
                short8 hdum;
                cvt8(Wx_w + (size_t)l * 65536 + (size_t)(wv * 32 + ni * 16 + ln15) * HDIM + kc * 32 + kq,
                     hdum, wxl[ni][kc]);
            }
        float bv[2];
#pragma unroll
        for (int ni = 0; ni < 2; ++ni) {
            const int col = wv * 32 + ni * 16 + ln15;
            bv[ni] = Wx_b[l * HDIM + col] + Wh_b[l * HDIM + col];
        }
        __syncthreads();

        int* fuMe = fu + ((l << 3) + j) * TSTEPS;
        int* fhW0 = fh + (l * 16 + 2 * j) * TSTEPS;          // u WAR: both rec consumers
        int* fhW1 = fh + (l * 16 + 2 * j + 1) * TSTEPS;
        int* fhX0 = (l > 0) ? fh + ((l - 1) * 16 + 2 * j) * TSTEPS : nullptr;
        int* fhX1 = (l > 0) ? fh + ((l - 1) * 16 + 2 * j + 1) * TSTEPS : nullptr;

        for (int t = t0; t < TSTEPS; t += tstr) {
            if (tid == 0) {
                if (fhX0) { wait_ge(fhX0 + t, 1); wait_ge(fhX1 + t, 1); }   // x(t) ready
                if (t >= DEPTH) { wait_ge(fhW0 + t - DEPTH, 1); wait_ge(fhW1 + t - DEPTH, 1); }
            }
            __syncthreads();
            f32x4 acc[2][2] = {};
            if (l == 0) {
                const int tok0 = tokens[(j * 32 + ln15) * TSTEPS + t];
                const int tok1 = tokens[(j * 32 + 16 + ln15) * TSTEPS + t];
                const float* e0 = emb + (size_t)tok0 * HDIM;
                const float* e1 = emb + (size_t)tok1 * HDIM;
#pragma unroll
                for (int kc = 0; kc < 8; ++kc) {
                    short8 ah0, al0, ah1, al1;
                    cvt8(e0 + kc * 32 + kq, ah0, al0);
                    cvt8(e1 + kc * 32 + kq, ah1, al1);
                    const int kb = (kc * 64 + hi16) ^ swz;
                    const short8 bh0 = *(const short8*)(smem + (wv * 32 + ln15) * 512 + kb);
                    const short8 bh1 = *(const short8*)(smem + (wv * 32 + 16 + ln15) * 512 + kb);
                    acc[0][0] = MFMA16(ah0, bh0, acc[0][0]);
                    acc[1][0] = MFMA16(ah1, bh0, acc[1][0]);
                    acc[0][1] = MFMA16(ah0, bh1, acc[0][1]);
                    acc[1][1] = MFMA16(ah1, bh1, acc[1][1]);
                    acc[0][0] = MFMA16(ah0, wxl[0][kc], acc[0][0]);
                    acc[1][0] = MFMA16(ah1, wxl[0][kc], acc[1][0]);
                    acc[0][1] = MFMA16(ah0, wxl[1][kc], acc[0][1]);
                    acc[1][1] = MFMA16(ah1, wxl[1][kc], acc[1][1]);
                    acc[0][0] = MFMA16(al0, bh0, acc[0][0]);
                    acc[1][0] = MFMA16(al1, bh0, acc[1][0]);
                    acc[0][1] = MFMA16(al0, bh1, acc[0][1]);
                    acc[1][1] = MFMA16(al1, bh1, acc[1][1]);
                }
            } else {
                unsigned long long* xp = (unsigned long long*)
                    (hg + ((size_t)(t % DEPTH) * 9 + (l - 1)) * 65536);
#pragma unroll
                for (int kc = 0; kc < 8; ++kc) {
                    short8 ah0, al0, ah1, al1;
                    ld_x8(xp + (((size_t)(j * 32 + ln15) * HDIM + kc * 32 + kq) >> 1), ah0, al0);
                    ld_x8(xp + (((size_t)(j * 32 + 16 + ln15) * HDIM + kc * 32 + kq) >> 1), ah1, al1);
                    const int kb = (kc * 64 + hi16) ^ swz;
                    const short8 bh0 = *(const short8*)(smem + (wv * 32 + ln15) * 512 + kb);
                    const short8 bh1 = *(const short8*)(smem + (wv * 32 + 16 + ln15) * 512 + kb);
                    acc[0][0] = MFMA16(ah0, bh0, acc[0][0]);
                    acc[1][0] = MFMA16(ah1, bh0, acc[1][0]);
                    acc[0][1] = MFMA16(ah0, bh1, acc[0][1]);
                    acc[1][1] = MFMA16(ah1, bh1, acc[1][1]);
                    acc[0][0] = MFMA16(ah0, wxl[0][kc], acc[0][0]);
                    acc[1][0] = MFMA16(ah1, wxl[0][kc], acc[1][0]);
                    acc[0][1] = MFMA16(ah0, wxl[1][kc], acc[0][1]);
                    acc[1][1] = MFMA16(ah1, wxl[1][kc], acc[1][1]);
                    acc[0][0] = MFMA16(al0, bh0, acc[0][0]);
                    acc[1][0] = MFMA16(al1, bh0, acc[1][0]);
                    acc[0][1] = MFMA16(al0, bh1, acc[0][1]);
                    acc[1][1] = MFMA16(al1, bh1, acc[1][1]);
                }
            }
            // u = acc + bias -> chains (l*16 + 2j + mi), fragment-linear sc1 stores
#pragma unroll
            for (int mi = 0; mi < 2; ++mi) {
                unsigned long long* us = (unsigned long long*)
                    (u + ((size_t)(t % DEPTH) * NB_REC + (l * 16 + 2 * j + mi)) * 4096);
#pragma unroll
                for (int ni = 0; ni < 2; ++ni) {
                    const size_t ix = ((size_t)((wv * 2 + ni) * 64 + lane)) * 2;
                    const float v0 = acc[mi][ni][0] + bv[ni];
                    const float v1 = acc[mi][ni][1] + bv[ni];
                    const float v2 = acc[mi][ni][2] + bv[ni];
                    const float v3 = acc[mi][ni][3] + bv[ni];
                    AT_ST(us + ix,     ((unsigned long long)__float_as_uint(v1) << 32) | __float_as_uint(v0));
                    AT_ST(us + ix + 1, ((unsigned long long)__float_as_uint(v3) << 32) | __float_as_uint(v2));
                }
            }
            VMDRAIN();
            __syncthreads();
            if (tid == 0)
                __hip_atomic_fetch_add(fuMe + t, 1, __ATOMIC_RELAXED, __HIP_MEMORY_SCOPE_AGENT);
        }
    }
}

// ---------- host ----------
extern "C" void kernel_launch(void* const* d_in, const int* in_sizes, int n_in,
                              void* d_out, int out_size, void* d_ws, size_t ws_size,
                              hipStream_t stream) {
    const int* tokens = (const int*)d_in[0];
    const float* hidden0 = (const float*)d_in[1];
    const float* emb = (const float*)d_in[2];
    const float* Wx_w = (const float*)d_in[3];
    const float* Wx_b = (const float*)d_in[4];
    const float* Wh_w = (const float*)d_in[5];
    const float* Wh_b = (const float*)d_in[6];
    float* out = (float*)d_out;

    char* ws = (char*)d_ws;
    size_t off = 0;
    auto carve = [&](size_t bytes) -> void* {
        void* p = ws + off;
        off = (off + bytes + 255) & ~(size_t)255;
        return p;
    };
    float* u = (float*)carve((size_t)DEPTH * NB_REC * 16 * HDIM * 4);      // 7.86 MB
    unsigned* hg = (unsigned*)carve((size_t)DEPTH * 9 * BATCH * HDIM * 4); // 7.08 MB
    int* fu = (int*)carve((size_t)80 * TSTEPS * 4);
    int* fh = (int*)carve((size_t)NB_REC * TSTEPS * 4);
    (void)ws_size; (void)in_sizes; (void)n_in; (void)out_size;

    hipMemsetAsync(fu, 0, (size_t)(80 + NB_REC) * TSTEPS * 4, stream);     // fu+fh contiguous

    void* args[] = { (void*)&tokens, (void*)&hidden0, (void*)&emb,
                     (void*)&Wx_w, (void*)&Wx_b, (void*)&Wh_w, (void*)&Wh_b,
                     (void*)&u, (void*)&hg, (void*)&fu, (void*)&fh, (void*)&out };
    hipLaunchCooperativeKernel((void*)rnn_pipe, dim3(NB_ALL), dim3(NTHR), args, 0, stream);
}

// Round 6
// 3939.192 us; speedup vs baseline: 2.1833x; 2.1833x over previous
//
#include <hip/hip_runtime.h>

#define HDIM   256
#define NLAYER 10
#define BATCH  256
#define TSTEPS 512
#define NTHR   512
#define DEPTH  8
#define NCH    160               // chains = 10 layers x 16 slices
#define NWG    160

typedef __attribute__((ext_vector_type(8))) short short8;
typedef __attribute__((ext_vector_type(4))) float f32x4;

// ---------- bf16 helpers ----------
__device__ __forceinline__ unsigned short bf16_rne(float f) {
    unsigned v = __float_as_uint(f);
    unsigned r = v + 0x7FFFu + ((v >> 16) & 1u);
    return (unsigned short)(r >> 16);
}
__device__ __forceinline__ float bf16_f(unsigned short b) {
    return __uint_as_float(((unsigned)b) << 16);
}
__device__ __forceinline__ float fast_tanh(float v) {
    float a = fabsf(v);
    float e = __expf(-2.0f * a);
    float r = (1.0f - e) / (1.0f + e);
    return __builtin_copysignf(r, v);
}
__device__ __forceinline__ void cvt8(const float* __restrict__ p, short8& hi, short8& lo) {
#pragma unroll
    for (int e = 0; e < 8; ++e) {
        float f = p[e];
        unsigned short h = bf16_rne(f);
        hi[e] = (short)h;
        lo[e] = (short)bf16_rne(f - bf16_f(h));
    }
}
__device__ __forceinline__ void cvt8v(const f32x4 a, const f32x4 b, short8& hi, short8& lo) {
#pragma unroll
    for (int i = 0; i < 4; ++i) {
        float f = a[i];
        unsigned short h = bf16_rne(f);
        hi[i] = (short)h; lo[i] = (short)bf16_rne(f - bf16_f(h));
    }
#pragma unroll
    for (int i = 0; i < 4; ++i) {
        float f = b[i];
        unsigned short h = bf16_rne(f);
        hi[4 + i] = (short)h; lo[4 + i] = (short)bf16_rne(f - bf16_f(h));
    }
}
__device__ __forceinline__ void unpack8(unsigned long long q0, unsigned long long q1,
                                        unsigned long long q2, unsigned long long q3,
                                        short8& hi, short8& lo) {
    unsigned long long q[4] = { q0, q1, q2, q3 };
#pragma unroll
    for (int i = 0; i < 4; ++i) {
        unsigned u0 = (unsigned)q[i], u1 = (unsigned)(q[i] >> 32);
        hi[2 * i]     = (short)(u0 & 0xffffu); lo[2 * i]     = (short)(u0 >> 16);
        hi[2 * i + 1] = (short)(u1 & 0xffffu); lo[2 * i + 1] = (short)(u1 >> 16);
    }
}

#define MFMA16(a, b, c) __builtin_amdgcn_mfma_f32_16x16x32_bf16((a), (b), (c), 0, 0, 0)

__device__ __forceinline__ void wait_ge(int* f, int need) {
    while (__hip_atomic_load(f, __ATOMIC_RELAXED, __HIP_MEMORY_SCOPE_AGENT) < need)
        __builtin_amdgcn_s_sleep(1);
}
#define AT_LD(p)    __hip_atomic_load((p), __ATOMIC_RELAXED, __HIP_MEMORY_SCOPE_AGENT)
#define AT_ST(p, v) __hip_atomic_store((p), (v), __ATOMIC_RELAXED, __HIP_MEMORY_SCOPE_AGENT)
#define VMDRAIN()   asm volatile("s_waitcnt vmcnt(0)" ::: "memory")

// LDS byte layout (160 KB total):
#define WXH 0        // Wx_hi swizzled [c 256][k 256] bf16       : 131072
#define HHI 131072   // h(t-1) hi [row 16][k 256] bf16, swizzled :   8192
#define HLO 139264   // h(t-1) lo                                :   8192
#define XHI 147456   // x(t) hi                                  :   8192
#define XLO 155648   // x(t) lo                                  :   8192

// ---------- single cooperative kernel: merged feed+rec, 1 hop/layer/step ----------
__global__ void __launch_bounds__(NTHR, 2) rnn_fused(
    const int* __restrict__ tokens, const float* __restrict__ hidden0,
    const float* __restrict__ emb,
    const float* __restrict__ Wx_w, const float* __restrict__ Wx_b,
    const float* __restrict__ Wh_w, const float* __restrict__ Wh_b,
    unsigned* __restrict__ hg,        // [DEPTH][NCH][16*256] packed (hi | lo<<16)
    int* __restrict__ fh,             // [NCH][TSTEPS]
    float* __restrict__ out) {
    const int bid = blockIdx.x;
    const int l = bid >> 4;
    const int s16 = bid & 15;
    const int c = bid;
    const int tid = threadIdx.x;
    const int wv = tid >> 6;
    const int lane = tid & 63;
    const int ln15 = lane & 15;
    const int kq = (lane >> 4) << 3;      // k element sub-offset
    const int hi16 = (lane >> 4) << 4;    // k byte sub-offset
    const int swz = (ln15 & 7) << 4;
    const int srow = tid >> 5;            // staging row 0..15
    const int scb = tid & 31;             // staging 16B chunk 0..31

    __shared__ char smem[163840];
    float* hfinal = out + (size_t)BATCH * TSTEPS * HDIM;

    // ---- stage Wx_hi -> LDS (swizzled) ----
    {
        const float* wxsrcA = Wx_w + (size_t)l * 65536;
        for (int i = 0; i < 16; ++i) {
            const int ch = tid + i * NTHR;
            const int r = ch >> 5, kb = ch & 31;
            short8 hi, lo;
            cvt8(wxsrcA + (size_t)r * HDIM + kb * 8, hi, lo);
            *(short8*)(smem + WXH + r * 512 + ((kb * 16) ^ ((r & 7) << 4))) = hi;
        }
    }
    // ---- weight registers: Wh hi/lo + Wx lo, macro-unrolled literal indices + pin ----
    short8 whh[2][8], whl[2][8], wxl[2][8];
    {
        const float* whsrc = Wh_w + (size_t)l * 65536;
        const float* wxsrc = Wx_w + (size_t)l * 65536;
#define WINIT(ni, kc) do { \
        short8 _d; \
        cvt8(whsrc + (size_t)(wv * 32 + ni * 16 + ln15) * HDIM + kc * 32 + kq, whh[ni][kc], whl[ni][kc]); \
        cvt8(wxsrc + (size_t)(wv * 32 + ni * 16 + ln15) * HDIM + kc * 32 + kq, _d, wxl[ni][kc]); \
        asm volatile("" : "+v"(whh[ni][kc]), "+v"(whl[ni][kc]), "+v"(wxl[ni][kc])); \
    } while (0)
        WINIT(0,0); WINIT(0,1); WINIT(0,2); WINIT(0,3);
        WINIT(0,4); WINIT(0,5); WINIT(0,6); WINIT(0,7);
        WINIT(1,0); WINIT(1,1); WINIT(1,2); WINIT(1,3);
        WINIT(1,4); WINIT(1,5); WINIT(1,6); WINIT(1,7);
#undef WINIT
    }
    // ---- h(-1) = hidden0 slice -> LDS hi/lo (1 chunk per thread) ----
    {
        short8 hi, lo;
        cvt8(hidden0 + ((size_t)(l * BATCH + s16 * 16 + srow)) * HDIM + scb * 8, hi, lo);
        const int so = srow * 512 + ((scb * 16) ^ ((srow & 7) << 4));
        *(short8*)(smem + HHI + so) = hi;
        *(short8*)(smem + HLO + so) = lo;
    }
    // ---- bias ----
    float bv[2];
#pragma unroll
    for (int ni = 0; ni < 2; ++ni) {
        const int col = wv * 32 + ni * 16 + ln15;
        bv[ni] = Wx_b[l * HDIM + col] + Wh_b[l * HDIM + col];
    }

    int* fhme = fh + (size_t)c * TSTEPS;
    int* fhp = (l > 0) ? fh + (size_t)(c - 16) * TSTEPS : nullptr;
    int* fhn = (l < NLAYER - 1) ? fh + (size_t)(c + 16) * TSTEPS : nullptr;

    // ---- prologue: stage x(0) ----
    if (l > 0) {
        if (tid == 0) wait_ge(fhp + 0, 1);
        __syncthreads();
        unsigned long long* xp = (unsigned long long*)
            (hg + ((size_t)0 * NCH + (c - 16)) * 4096) + (size_t)tid * 4;
        unsigned long long q0 = AT_LD(xp), q1 = AT_LD(xp + 1),
                           q2 = AT_LD(xp + 2), q3 = AT_LD(xp + 3);
        short8 sxh, sxl;
        unpack8(q0, q1, q2, q3, sxh, sxl);
        const int so = srow * 512 + ((scb * 16) ^ ((srow & 7) << 4));
        *(short8*)(smem + XHI + so) = sxh;
        *(short8*)(smem + XLO + so) = sxl;
    } else {
        const int tok = tokens[(s16 * 16 + srow) * TSTEPS + 0];
        const float* ep = emb + (size_t)tok * HDIM + scb * 8;
        short8 sxh, sxl;
        cvt8(ep, sxh, sxl);
        const int so = srow * 512 + ((scb * 16) ^ ((srow & 7) << 4));
        *(short8*)(smem + XHI + so) = sxh;
        *(short8*)(smem + XLO + so) = sxl;
    }
    __syncthreads();   // all staging visible

    // ---- main loop ----
    for (int t = 0; t < TSTEPS; ++t) {
        // TOP: gate x(t+1) issue + hg(t) WAR
        if (tid == 0) {
            if (l > 0 && t + 1 < TSTEPS) wait_ge(fhp + (t + 1), 1);
            if (fhn && t >= DEPTH) wait_ge(fhn + (t - DEPTH), 1);
        }
        __syncthreads();

        // A: issue x(t+1) loads (held in regs until G)
        unsigned long long q0 = 0, q1 = 0, q2 = 0, q3 = 0;
        f32x4 ef0 = {}, ef1 = {};
        if (t + 1 < TSTEPS) {
            if (l > 0) {
                unsigned long long* xp = (unsigned long long*)
                    (hg + ((size_t)((t + 1) % DEPTH) * NCH + (c - 16)) * 4096) + (size_t)tid * 4;
                q0 = AT_LD(xp); q1 = AT_LD(xp + 1); q2 = AT_LD(xp + 2); q3 = AT_LD(xp + 3);
            } else {
                const int tok = tokens[(s16 * 16 + srow) * TSTEPS + (t + 1)];
                const float* ep = emb + (size_t)tok * HDIM + scb * 8;
                ef0 = *(const f32x4*)ep;
                ef1 = *(const f32x4*)(ep + 4);
            }
        }

        // B+C: acc = h(t-1)@Wh^T + x(t)@Wx^T   (12 MFMA per kc, macro-unrolled)
        f32x4 acc0 = {}, acc1 = {};
#define HX_KC(kc) do { \
        const int _off = ((kc) * 64 + hi16) ^ swz; \
        const short8 hh  = *(const short8*)(smem + HHI + ln15 * 512 + _off); \
        const short8 hl  = *(const short8*)(smem + HLO + ln15 * 512 + _off); \
        const short8 xh  = *(const short8*)(smem + XHI + ln15 * 512 + _off); \
        const short8 xl  = *(const short8*)(smem + XLO + ln15 * 512 + _off); \
        const short8 bh0 = *(const short8*)(smem + WXH + (wv * 32 + ln15) * 512 + _off); \
        const short8 bh1 = *(const short8*)(smem + WXH + (wv * 32 + 16 + ln15) * 512 + _off); \
        acc0 = MFMA16(hh, whh[0][kc], acc0);  acc1 = MFMA16(hh, whh[1][kc], acc1); \
        acc0 = MFMA16(hh, whl[0][kc], acc0);  acc1 = MFMA16(hh, whl[1][kc], acc1); \
        acc0 = MFMA16(hl, whh[0][kc], acc0);  acc1 = MFMA16(hl, whh[1][kc], acc1); \
        acc0 = MFMA16(xh, bh0, acc0);         acc1 = MFMA16(xh, bh1, acc1); \
        acc0 = MFMA16(xh, wxl[0][kc], acc0);  acc1 = MFMA16(xh, wxl[1][kc], acc1); \
        acc0 = MFMA16(xl, bh0, acc0);         acc1 = MFMA16(xl, bh1, acc1); \
    } while (0)
        HX_KC(0); HX_KC(1); HX_KC(2); HX_KC(3);
        HX_KC(4); HX_KC(5); HX_KC(6); HX_KC(7);
#undef HX_KC

        // D: tanh + pack into regs
        unsigned pk[2][4];
        float yf[2][4];
#pragma unroll
        for (int ni = 0; ni < 2; ++ni) {
            const f32x4 a = (ni == 0) ? acc0 : acc1;
#pragma unroll
            for (int r = 0; r < 4; ++r) {
                const float y = fast_tanh(a[r] + bv[ni]);
                const unsigned short yh = bf16_rne(y);
                const unsigned short yl = bf16_rne(y - bf16_f(yh));
                pk[ni][r] = (unsigned)yh | ((unsigned)yl << 16);
                yf[ni][r] = y;
            }
        }

        VMDRAIN();          // E: x(t+1) loads arrived
        __syncthreads();    // F: all LDS reads of h(t-1), x(t) complete

        // G: LDS writes (h(t), x(t+1)) + global publishes
        {
            unsigned* hgw = (fhn) ? hg + ((size_t)(t % DEPTH) * NCH + c) * 4096 : nullptr;
#pragma unroll
            for (int ni = 0; ni < 2; ++ni) {
                const int col = wv * 32 + ni * 16 + ln15;
#pragma unroll
                for (int r = 0; r < 4; ++r) {
                    const int row = ((lane >> 4) << 2) + r;
                    const int so = row * 512 + ((2 * col) ^ ((row & 7) << 4));
                    *(unsigned short*)(smem + HHI + so) = (unsigned short)(pk[ni][r] & 0xffffu);
                    *(unsigned short*)(smem + HLO + so) = (unsigned short)(pk[ni][r] >> 16);
                    if (hgw) {
                        AT_ST(hgw + (size_t)row * HDIM + col, pk[ni][r]);
                    } else {
                        out[((size_t)(s16 * 16 + row) * TSTEPS + t) * HDIM + col] = yf[ni][r];
                    }
                    if (t == TSTEPS - 1)
                        hfinal[((size_t)l * BATCH + s16 * 16 + row) * HDIM + col] = yf[ni][r];
                }
            }
            if (t + 1 < TSTEPS) {
                short8 sxh, sxl;
                if (l > 0) unpack8(q0, q1, q2, q3, sxh, sxl);
                else       cvt8v(ef0, ef1, sxh, sxl);
                const int so = srow * 512 + ((scb * 16) ^ ((srow & 7) << 4));
                *(short8*)(smem + XHI + so) = sxh;
                *(short8*)(smem + XLO + so) = sxl;
            }
        }

        VMDRAIN();          // H: global stores at coherence point
        __syncthreads();    // I: all threads drained + LDS written
        if (tid == 0)       // J: publish
            __hip_atomic_fetch_add(fhme + t, 1, __ATOMIC_RELAXED, __HIP_MEMORY_SCOPE_AGENT);
    }
}

// ---------- host ----------
extern "C" void kernel_launch(void* const* d_in, const int* in_sizes, int n_in,
                              void* d_out, int out_size, void* d_ws, size_t ws_size,
                              hipStream_t stream) {
    const int* tokens = (const int*)d_in[0];
    const float* hidden0 = (const float*)d_in[1];
    const float* emb = (const float*)d_in[2];
    const float* Wx_w = (const float*)d_in[3];
    const float* Wx_b = (const float*)d_in[4];
    const float* Wh_w = (const float*)d_in[5];
    const float* Wh_b = (const float*)d_in[6];
    float* out = (float*)d_out;

    char* ws = (char*)d_ws;
    size_t off = 0;
    auto carve = [&](size_t bytes) -> void* {
        void* p = ws + off;
        off = (off + bytes + 255) & ~(size_t)255;
        return p;
    };
    unsigned* hg = (unsigned*)carve((size_t)DEPTH * NCH * 16 * HDIM * 4);  // 21.0 MB
    int* fh = (int*)carve((size_t)NCH * TSTEPS * 4);                       // 0.33 MB
    (void)ws_size; (void)in_sizes; (void)n_in; (void)out_size;

    hipMemsetAsync(fh, 0, (size_t)NCH * TSTEPS * 4, stream);

    void* args[] = { (void*)&tokens, (void*)&hidden0, (void*)&emb,
                     (void*)&Wx_w, (void*)&Wx_b, (void*)&Wh_w, (void*)&Wh_b,
                     (void*)&hg, (void*)&fh, (void*)&out };
    hipLaunchCooperativeKernel((void*)rnn_fused, dim3(NWG), dim3(NTHR), args, 0, stream);
}

// Round 7
// 3405.525 us; speedup vs baseline: 2.5254x; 1.1567x over previous
//
#include <hip/hip_runtime.h>

#define HDIM   256
#define NLAYER 10
#define BATCH  256
#define TSTEPS 512
#define NTHR   512
#define DEPTH  8
#define NCH    160               // chains = 10 layers x 16 slices
#define NWG    160

typedef __attribute__((ext_vector_type(8))) short short8;
typedef __attribute__((ext_vector_type(4))) float f32x4;

// ---------- bf16 helpers ----------
__device__ __forceinline__ unsigned short bf16_rne(float f) {
    unsigned v = __float_as_uint(f);
    unsigned r = v + 0x7FFFu + ((v >> 16) & 1u);
    return (unsigned short)(r >> 16);
}
__device__ __forceinline__ float bf16_f(unsigned short b) {
    return __uint_as_float(((unsigned)b) << 16);
}
__device__ __forceinline__ float fast_tanh(float v) {
    float a = fabsf(v);
    float e = __expf(-2.0f * a);
    float r = (1.0f - e) / (1.0f + e);
    return __builtin_copysignf(r, v);
}
__device__ __forceinline__ void cvt8(const float* __restrict__ p, short8& hi, short8& lo) {
#pragma unroll
    for (int e = 0; e < 8; ++e) {
        float f = p[e];
        unsigned short h = bf16_rne(f);
        hi[e] = (short)h;
        lo[e] = (short)bf16_rne(f - bf16_f(h));
    }
}
// 8 floats carried as 4 u64 -> hi/lo bf16 fragments
__device__ __forceinline__ void cvtq(unsigned long long q0, unsigned long long q1,
                                     unsigned long long q2, unsigned long long q3,
                                     short8& hi, short8& lo) {
    unsigned long long q[4] = { q0, q1, q2, q3 };
#pragma unroll
    for (int i = 0; i < 4; ++i) {
#pragma unroll
        for (int j = 0; j < 2; ++j) {
            const float f = __uint_as_float((unsigned)(q[i] >> (32 * j)));
            const unsigned short h = bf16_rne(f);
            hi[2 * i + j] = (short)h;
            lo[2 * i + j] = (short)bf16_rne(f - bf16_f(h));
        }
    }
}
// 4 u64 of packed (hi | lo<<16) -> hi/lo fragments
__device__ __forceinline__ void unpack8(unsigned long long q0, unsigned long long q1,
                                        unsigned long long q2, unsigned long long q3,
                                        short8& hi, short8& lo) {
    unsigned long long q[4] = { q0, q1, q2, q3 };
#pragma unroll
    for (int i = 0; i < 4; ++i) {
        unsigned u0 = (unsigned)q[i], u1 = (unsigned)(q[i] >> 32);
        hi[2 * i]     = (short)(u0 & 0xffffu); lo[2 * i]     = (short)(u0 >> 16);
        hi[2 * i + 1] = (short)(u1 & 0xffffu); lo[2 * i + 1] = (short)(u1 >> 16);
    }
}

#define MFMA16(a, b, c) __builtin_amdgcn_mfma_f32_16x16x32_bf16((a), (b), (c), 0, 0, 0)

__device__ __forceinline__ void wait_ge(int* f, int need) {
    while (__hip_atomic_load(f, __ATOMIC_RELAXED, __HIP_MEMORY_SCOPE_AGENT) < need)
        __builtin_amdgcn_s_sleep(1);
}
#define AT_LD(p)    __hip_atomic_load((p), __ATOMIC_RELAXED, __HIP_MEMORY_SCOPE_AGENT)
#define AT_ST(p, v) __hip_atomic_store((p), (v), __ATOMIC_RELAXED, __HIP_MEMORY_SCOPE_AGENT)
#define VMDRAIN()   asm volatile("s_waitcnt vmcnt(0)" ::: "memory")

// LDS byte layout (160 KB total):
#define WXH 0        // Wx_hi swizzled [c 256][k 256] bf16       : 131072
#define HHI 131072   // h(t-1) hi [row 16][k 256] bf16, swizzled :   8192
#define HLO 139264   // h(t-1) lo                                :   8192
#define XHI 147456   // x(t) hi                                  :   8192
#define XLO 155648   // x(t) lo                                  :   8192

// ---------- single cooperative kernel: merged feed+rec, deferred publish ----------
__global__ void __launch_bounds__(NTHR, 2) rnn_fused(
    const int* __restrict__ tokens, const float* __restrict__ hidden0,
    const float* __restrict__ emb,
    const float* __restrict__ Wx_w, const float* __restrict__ Wx_b,
    const float* __restrict__ Wh_w, const float* __restrict__ Wh_b,
    unsigned* __restrict__ hg,        // [DEPTH][NCH][16*256] packed (hi | lo<<16)
    int* __restrict__ fh,             // [NCH][TSTEPS]
    float* __restrict__ out) {
    const int bid = blockIdx.x;
    const int l = bid >> 4;
    const int s16 = bid & 15;
    const int c = bid;
    const int tid = threadIdx.x;
    const int wv = tid >> 6;
    const int lane = tid & 63;
    const int ln15 = lane & 15;
    const int kq = (lane >> 4) << 3;      // k element sub-offset
    const int hi16 = (lane >> 4) << 4;    // k byte sub-offset
    const int swz = (ln15 & 7) << 4;
    const int srow = tid >> 5;            // staging row 0..15
    const int scb = tid & 31;             // staging 16B chunk 0..31

    __shared__ char smem[163840];
    float* hfinal = out + (size_t)BATCH * TSTEPS * HDIM;

    // ---- stage Wx_hi -> LDS (swizzled) ----
    {
        const float* wxsrcA = Wx_w + (size_t)l * 65536;
        for (int i = 0; i < 16; ++i) {
            const int ch = tid + i * NTHR;
            const int r = ch >> 5, kb = ch & 31;
            short8 hi, lo;
            cvt8(wxsrcA + (size_t)r * HDIM + kb * 8, hi, lo);
            *(short8*)(smem + WXH + r * 512 + ((kb * 16) ^ ((r & 7) << 4))) = hi;
        }
    }
    // ---- weight registers: Wh hi/lo + Wx lo, macro-unrolled literal indices + pin ----
    short8 whh[2][8], whl[2][8], wxl[2][8];
    {
        const float* whsrc = Wh_w + (size_t)l * 65536;
        const float* wxsrc = Wx_w + (size_t)l * 65536;
#define WINIT(ni, kc) do { \
        short8 _d; \
        cvt8(whsrc + (size_t)(wv * 32 + ni * 16 + ln15) * HDIM + kc * 32 + kq, whh[ni][kc], whl[ni][kc]); \
        cvt8(wxsrc + (size_t)(wv * 32 + ni * 16 + ln15) * HDIM + kc * 32 + kq, _d, wxl[ni][kc]); \
        asm volatile("" : "+v"(whh[ni][kc]), "+v"(whl[ni][kc]), "+v"(wxl[ni][kc])); \
    } while (0)
        WINIT(0,0); WINIT(0,1); WINIT(0,2); WINIT(0,3);
        WINIT(0,4); WINIT(0,5); WINIT(0,6); WINIT(0,7);
        WINIT(1,0); WINIT(1,1); WINIT(1,2); WINIT(1,3);
        WINIT(1,4); WINIT(1,5); WINIT(1,6); WINIT(1,7);
#undef WINIT
    }
    // ---- h(-1) = hidden0 slice -> LDS hi/lo (1 chunk per thread) ----
    {
        short8 hi, lo;
        cvt8(hidden0 + ((size_t)(l * BATCH + s16 * 16 + srow)) * HDIM + scb * 8, hi, lo);
        const int so = srow * 512 + ((scb * 16) ^ ((srow & 7) << 4));
        *(short8*)(smem + HHI + so) = hi;
        *(short8*)(smem + HLO + so) = lo;
    }
    // ---- bias ----
    float bv[2];
#pragma unroll
    for (int ni = 0; ni < 2; ++ni) {
        const int col = wv * 32 + ni * 16 + ln15;
        bv[ni] = Wx_b[l * HDIM + col] + Wh_b[l * HDIM + col];
    }

    int* fhme = fh + (size_t)c * TSTEPS;
    int* fhp = (l > 0) ? fh + (size_t)(c - 16) * TSTEPS : nullptr;
    int* fhn = (l < NLAYER - 1) ? fh + (size_t)(c + 16) * TSTEPS : nullptr;

    // ---- prologue: stage x(0) ----
    if (l > 0) {
        if (tid == 0) wait_ge(fhp + 0, 1);
        __syncthreads();
        unsigned long long* xp = (unsigned long long*)
            (hg + ((size_t)0 * NCH + (c - 16)) * 4096) + (size_t)tid * 4;
        unsigned long long q0 = AT_LD(xp), q1 = AT_LD(xp + 1),
                           q2 = AT_LD(xp + 2), q3 = AT_LD(xp + 3);
        short8 sxh, sxl;
        unpack8(q0, q1, q2, q3, sxh, sxl);
        const int so = srow * 512 + ((scb * 16) ^ ((srow & 7) << 4));
        *(short8*)(smem + XHI + so) = sxh;
        *(short8*)(smem + XLO + so) = sxl;
    } else {
        const int tok = tokens[(s16 * 16 + srow) * TSTEPS + 0];
        const float* ep = emb + (size_t)tok * HDIM + scb * 8;
        short8 sxh, sxl;
        cvt8(ep, sxh, sxl);
        const int so = srow * 512 + ((scb * 16) ^ ((srow & 7) << 4));
        *(short8*)(smem + XHI + so) = sxh;
        *(short8*)(smem + XLO + so) = sxl;
    }
    __syncthreads();   // all staging visible

    // ---- main loop ----
    // WAR proof: writer overwrites hg slot t%8 (h(t) over h(t-8)) in G of step t.
    // Consumer issued its loads of h(t-8) at A of its step t-9, drained them at its
    // mid-step VMDRAIN of step t-9, and its flag(t-9) (published in its G of step t-8,
    // after that drain + barrier) therefore attests the reads. Guard: wait fhn[t-9].
    for (int t = 0; t < TSTEPS; ++t) {
        // TOP: parallel polls, then one barrier
        if (tid == 0 && l > 0 && t + 1 < TSTEPS) wait_ge(fhp + (t + 1), 1);
        if (tid == 64 && fhn && t >= 9) wait_ge(fhn + (t - 9), 1);
        __syncthreads();

        // A: issue x(t+1) loads (held in regs until G)
        unsigned long long q0 = 0, q1 = 0, q2 = 0, q3 = 0;
        if (t + 1 < TSTEPS) {
            if (l > 0) {
                unsigned long long* xp = (unsigned long long*)
                    (hg + ((size_t)((t + 1) % DEPTH) * NCH + (c - 16)) * 4096) + (size_t)tid * 4;
                q0 = AT_LD(xp); q1 = AT_LD(xp + 1); q2 = AT_LD(xp + 2); q3 = AT_LD(xp + 3);
            } else {
                const int tok = tokens[(s16 * 16 + srow) * TSTEPS + (t + 1)];
                const unsigned long long* ep =
                    (const unsigned long long*)(emb + (size_t)tok * HDIM + scb * 8);
                q0 = ep[0]; q1 = ep[1]; q2 = ep[2]; q3 = ep[3];
            }
        }

        // B+C: acc = h(t-1)@Wh^T + x(t)@Wx^T   (12 MFMA per kc, macro-unrolled)
        f32x4 acc0 = {}, acc1 = {};
#define HX_KC(kc) do { \
        const int _off = ((kc) * 64 + hi16) ^ swz; \
        const short8 hh  = *(const short8*)(smem + HHI + ln15 * 512 + _off); \
        const short8 hl  = *(const short8*)(smem + HLO + ln15 * 512 + _off); \
        const short8 xh  = *(const short8*)(smem + XHI + ln15 * 512 + _off); \
        const short8 xl  = *(const short8*)(smem + XLO + ln15 * 512 + _off); \
        const short8 bh0 = *(const short8*)(smem + WXH + (wv * 32 + ln15) * 512 + _off); \
        const short8 bh1 = *(const short8*)(smem + WXH + (wv * 32 + 16 + ln15) * 512 + _off); \
        acc0 = MFMA16(hh, whh[0][kc], acc0);  acc1 = MFMA16(hh, whh[1][kc], acc1); \
        acc0 = MFMA16(hh, whl[0][kc], acc0);  acc1 = MFMA16(hh, whl[1][kc], acc1); \
        acc0 = MFMA16(hl, whh[0][kc], acc0);  acc1 = MFMA16(hl, whh[1][kc], acc1); \
        acc0 = MFMA16(xh, bh0, acc0);         acc1 = MFMA16(xh, bh1, acc1); \
        acc0 = MFMA16(xh, wxl[0][kc], acc0);  acc1 = MFMA16(xh, wxl[1][kc], acc1); \
        acc0 = MFMA16(xl, bh0, acc0);         acc1 = MFMA16(xl, bh1, acc1); \
    } while (0)
        HX_KC(0); HX_KC(1); HX_KC(2); HX_KC(3);
        HX_KC(4); HX_KC(5); HX_KC(6); HX_KC(7);
#undef HX_KC

        // D: tanh + pack (no separate float copy; y reconstructed from hi+lo)
        unsigned pk[2][4];
#pragma unroll
        for (int ni = 0; ni < 2; ++ni) {
            const f32x4 a = (ni == 0) ? acc0 : acc1;
#pragma unroll
            for (int r = 0; r < 4; ++r) {
                const float y = fast_tanh(a[r] + bv[ni]);
                const unsigned short yh = bf16_rne(y);
                const unsigned short yl = bf16_rne(y - bf16_f(yh));
                pk[ni][r] = (unsigned)yh | ((unsigned)yl << 16);
            }
        }

        VMDRAIN();          // x(t+1) loads arrived; h(t-1)/out stores (issued last step) done
        __syncthreads();    // all waves drained + all LDS reads of h(t-1), x(t) complete

        // G: publish flag(t-1); LDS writes h(t), x(t+1); issue global stores of h(t)
        if (tid == 0 && t > 0)
            AT_ST(fhme + (t - 1), 1);
        {
            unsigned* hgw = (fhn) ? hg + ((size_t)(t % DEPTH) * NCH + c) * 4096 : nullptr;
#pragma unroll
            for (int ni = 0; ni < 2; ++ni) {
                const int col = wv * 32 + ni * 16 + ln15;
#pragma unroll
                for (int r = 0; r < 4; ++r) {
                    const int row = ((lane >> 4) << 2) + r;
                    const int so = row * 512 + ((2 * col) ^ ((row & 7) << 4));
                    *(unsigned short*)(smem + HHI + so) = (unsigned short)(pk[ni][r] & 0xffffu);
                    *(unsigned short*)(smem + HLO + so) = (unsigned short)(pk[ni][r] >> 16);
                    if (hgw) {
                        AT_ST(hgw + (size_t)row * HDIM + col, pk[ni][r]);
                    } else {
                        const float y = bf16_f((unsigned short)(pk[ni][r] & 0xffffu)) +
                                        bf16_f((unsigned short)(pk[ni][r] >> 16));
                        out[((size_t)(s16 * 16 + row) * TSTEPS + t) * HDIM + col] = y;
                    }
                    if (t == TSTEPS - 1) {
                        const float y = bf16_f((unsigned short)(pk[ni][r] & 0xffffu)) +
                                        bf16_f((unsigned short)(pk[ni][r] >> 16));
                        hfinal[((size_t)l * BATCH + s16 * 16 + row) * HDIM + col] = y;
                    }
                }
            }
            if (t + 1 < TSTEPS) {
                short8 sxh, sxl;
                if (l > 0) unpack8(q0, q1, q2, q3, sxh, sxl);
                else       cvtq(q0, q1, q2, q3, sxh, sxl);
                const int so = srow * 512 + ((scb * 16) ^ ((srow & 7) << 4));
                *(short8*)(smem + XHI + so) = sxh;
                *(short8*)(smem + XLO + so) = sxl;
            }
        }
        // next iteration's TOP barrier separates these LDS writes from the next reads
    }
    // epilogue: final flag after draining the last hg stores
    VMDRAIN();
    __syncthreads();
    if (tid == 0) AT_ST(fhme + (TSTEPS - 1), 1);
}

// ---------- host ----------
extern "C" void kernel_launch(void* const* d_in, const int* in_sizes, int n_in,
                              void* d_out, int out_size, void* d_ws, size_t ws_size,
                              hipStream_t stream) {
    const int* tokens = (const int*)d_in[0];
    const float* hidden0 = (const float*)d_in[1];
    const float* emb = (const float*)d_in[2];
    const float* Wx_w = (const float*)d_in[3];
    const float* Wx_b = (const float*)d_in[4];
    const float* Wh_w = (const float*)d_in[5];
    const float* Wh_b = (const float*)d_in[6];
    float* out = (float*)d_out;

    char* ws = (char*)d_ws;
    size_t off = 0;
    auto carve = [&](size_t bytes) -> void* {
        void* p = ws + off;
        off = (off + bytes + 255) & ~(size_t)255;
        return p;
    };
    unsigned* hg = (unsigned*)carve((size_t)DEPTH * NCH * 16 * HDIM * 4);  // 21.0 MB
    int* fh = (int*)carve((size_t)NCH * TSTEPS * 4);                       // 0.33 MB
    (void)ws_size; (void)in_sizes; (void)n_in; (void)out_size;

    hipMemsetAsync(fh, 0, (size_t)NCH * TSTEPS * 4, stream);

    void* args[] = { (void*)&tokens, (void*)&hidden0, (void*)&emb,
                     (void*)&Wx_w, (void*)&Wx_b, (void*)&Wh_w, (void*)&Wh_b,
                     (void*)&hg, (void*)&fh, (void*)&out };
    hipLaunchCooperativeKernel((void*)rnn_fused, dim3(NWG), dim3(NTHR), args, 0, stream);
}